// Round 11
// baseline (166.456 us; speedup 1.0000x reference)
//
#include <hip/hip_runtime.h>

#define NTOK 1024
#define DDIM 128

typedef _Float16 f16;
typedef _Float16 f16x2v __attribute__((ext_vector_type(2)));
typedef _Float16 f16x4 __attribute__((ext_vector_type(4)));
typedef _Float16 f16x8 __attribute__((ext_vector_type(8)));
typedef float f32x16 __attribute__((ext_vector_type(16)));
typedef unsigned int uint;
typedef unsigned long u64;
typedef long i64;
typedef long i64x2 __attribute__((ext_vector_type(2)));

union PFrag {
  float f[4];
  f16x8 h;
};

#define NLOG2E -1.44269504f

// ---------------- fused prepass ---------------------------------------------
// blocks [0,1024):    x -> x8f (normalized fp8, GEMM1 fragment layout)
//                        -> xtf (unscaled f16 X^T, GEMM2-A fragment layout)
// blocks [1024,1280): beta -> betaTf (f16 pairs, fragment layout, -log2e):
//   uint4 idx = (((bj*2+ms)*32 + it2)*2 + ch)*64 + lane2   (2 MB exact)
__global__ __launch_bounds__(256) void prep_fused(
    const float* __restrict__ x, const float* __restrict__ beta,
    unsigned char* __restrict__ x8f, f16* __restrict__ xtf,
    uint* __restrict__ betaTf) {
  __shared__ __align__(16) char psm[17408];
  int bx = blockIdx.x;
  int t = threadIdx.x;
  if (bx < 1024) {
    f16* sT = (f16*)psm;  // [64][132]
    int bc = bx & 63;
    int nt = bx >> 6;  // 0..15  (= mi)
    int n0 = nt * 64;
    const float4* xv = (const float4*)(x + ((size_t)bc * NTOK + n0) * DDIM);
    int rbase = t >> 3;  // 0..31
    int c = t & 7;       // 16-byte chunk = kk
#pragma unroll
    for (int rr = 0; rr < 64; rr += 32) {
      int row = rbase + rr;
      float4 v0 = xv[(size_t)row * 32 + c * 4 + 0];
      float4 v1 = xv[(size_t)row * 32 + c * 4 + 1];
      float4 v2 = xv[(size_t)row * 32 + c * 4 + 2];
      float4 v3 = xv[(size_t)row * 32 + c * 4 + 3];
      float ss = v0.x * v0.x + v0.y * v0.y + v0.z * v0.z + v0.w * v0.w;
      ss += v1.x * v1.x + v1.y * v1.y + v1.z * v1.z + v1.w * v1.w;
      ss += v2.x * v2.x + v2.y * v2.y + v2.z * v2.z + v2.w * v2.w;
      ss += v3.x * v3.x + v3.y * v3.y + v3.z * v3.z + v3.w * v3.w;
      ss += __shfl_xor(ss, 1);
      ss += __shfl_xor(ss, 2);
      ss += __shfl_xor(ss, 4);
      float rn = (ss > 0.f) ? rsqrtf(ss) : 0.f;
      uint pa, pb, pc, pd;
      {
        int a;
        a = __builtin_amdgcn_cvt_pk_fp8_f32(v0.x * rn, v0.y * rn, 0, false);
        pa = __builtin_amdgcn_cvt_pk_fp8_f32(v0.z * rn, v0.w * rn, a, true);
        a = __builtin_amdgcn_cvt_pk_fp8_f32(v1.x * rn, v1.y * rn, 0, false);
        pb = __builtin_amdgcn_cvt_pk_fp8_f32(v1.z * rn, v1.w * rn, a, true);
        a = __builtin_amdgcn_cvt_pk_fp8_f32(v2.x * rn, v2.y * rn, 0, false);
        pc = __builtin_amdgcn_cvt_pk_fp8_f32(v2.z * rn, v2.w * rn, a, true);
        a = __builtin_amdgcn_cvt_pk_fp8_f32(v3.x * rn, v3.y * rn, 0, false);
        pd = __builtin_amdgcn_cvt_pk_fp8_f32(v3.z * rn, v3.w * rn, a, true);
      }
      {
        int mb = nt * 2 + (row >> 5);
        int r31 = row & 31;
        size_t base =
            (((size_t)(bc * 32 + mb) * 4 + (c >> 1)) << 10) + ((c & 1) << 3);
        u64 lo = ((u64)pb << 32) | pa;
        u64 hig = ((u64)pd << 32) | pc;
        *(u64*)(x8f + base + (size_t)r31 * 16) = lo;
        *(u64*)(x8f + base + (size_t)(32 + r31) * 16) = hig;
      }
      f16x8 h0 = {(f16)v0.x, (f16)v0.y, (f16)v0.z, (f16)v0.w,
                  (f16)v1.x, (f16)v1.y, (f16)v1.z, (f16)v1.w};
      f16x8 h1 = {(f16)v2.x, (f16)v2.y, (f16)v2.z, (f16)v2.w,
                  (f16)v3.x, (f16)v3.y, (f16)v3.z, (f16)v3.w};
      *(f16x8*)(sT + row * 132 + c * 16) = h0;
      *(f16x8*)(sT + row * 132 + c * 16 + 8) = h1;
    }
    __syncthreads();
    // xtf gather: 4 entries of 16B per thread
#pragma unroll
    for (int q = 0; q < 4; ++q) {
      int e = t + 256 * q;
      int lane = e & 63;
      int dt = (e >> 6) & 3;
      int pair = (e >> 8) & 1;
      int ms = (e >> 9) & 1;
      int el31 = lane & 31;
      int ehi = lane >> 5;
      f16x8 v;
#pragma unroll
      for (int j = 0; j < 8; ++j)
        v[j] = sT[(ms * 32 + pair * 16 + ehi * 8 + j) * 132 + dt * 32 + el31];
      size_t off = ((((size_t)bc * 16 + nt) * 2 + ms) * 2 + pair) * 4 + dt;
      *(f16x8*)(xtf + (off * 64 + lane) * 8) = v;
    }
  } else {
    float(*s)[65] = (float(*)[65])psm;
    int bb = bx - 1024;
    int bi = bb & 15;  // i tile (64 i)
    int bj = bb >> 4;  // m tile (64 m = 32 pairs) -> mi = bj
    int r = t >> 4;
    int c4 = (t & 15) * 4;
#pragma unroll
    for (int rr = 0; rr < 64; rr += 16) {
      float4 v = *(const float4*)(beta + (size_t)(bi * 64 + r + rr) * NTOK +
                                  bj * 64 + c4);
      s[r + rr][c4] = v.x;
      s[r + rr][c4 + 1] = v.y;
      s[r + rr][c4 + 2] = v.z;
      s[r + rr][c4 + 3] = v.w;
    }
    __syncthreads();
    int il = t & 63;
#pragma unroll
    for (int rr = 0; rr < 8; ++rr) {
      int m2 = (t >> 6) + 4 * rr;  // 0..31 local pair index
      float b0 = s[il][2 * m2] * NLOG2E;
      float b1 = s[il][2 * m2 + 1] * NLOG2E;
      uint u = __builtin_bit_cast(uint, __builtin_amdgcn_cvt_pkrtz(b0, b1));
      int ms = m2 >> 4;
      int m2l = m2 & 15;
      int hi2 = (m2l >> 1) & 1;
      int rp = (m2l >> 2) * 2 + (m2l & 1);
      int ch = rp >> 2;
      int j = rp & 3;
      int it2 = bi * 2 + (il >> 5);  // 0..31
      int lane2 = hi2 * 32 + (il & 31);
      size_t didx =
          ((((size_t)(bj * 2 + ms) * 32 + it2) * 2 + ch) * 64 + lane2) * 4 + j;
      betaTf[didx] = u;
    }
  }
}

// ---------------- main ------------------------------------------------------
// 1024 blocks, barrier-free K-loop, all operands streamed from global in
// fragment layout. Pipelined by consumption order: a8 (GEMM1) double-buffered
// one iter ahead; beta (2 b128) + g2a issued at iter top, consumed after
// GEMM1/sigmoid so in-order vmcnt never stalls on them.
__global__ __launch_bounds__(256, 3) void cos_att_main(
    const unsigned char* __restrict__ x8f, const f16* __restrict__ xtf,
    const uint* __restrict__ betaTf, float* __restrict__ out) {
  __shared__ float sO[64 * 132];  // epilogue only (33792 B)
  int bx = blockIdx.x;
  int bc = bx >> 4;  // co-resident blocks share bc
  int qt = bx & 15;
  int q0 = qt * 64;

  int t = threadIdx.x;
  int lane = t & 63;
  int w = t >> 6;
  int l31 = lane & 31;
  int hi = lane >> 5;
  int i_str = (w >> 1) * 32;
  int it = qt * 2 + (w >> 1);  // global 32-row i-tile index, 0..31
  int ms = w & 1;

  // Xq B-frags (fp8): 4 coalesced b128 loads
  i64 xq8[8];
  {
    const i64x2* pq =
        (const i64x2*)(x8f +
                       (((size_t)(bc * 32 + qt * 2 + (i_str >> 5)) * 4) << 10) +
                       (size_t)lane * 16);
#pragma unroll
    for (int g = 0; g < 4; ++g) {
      i64x2 v = pq[g * 64];
      xq8[2 * g] = v[0];
      xq8[2 * g + 1] = v[1];
    }
  }

  // streaming pointers
  const i64x2* pG1 = (const i64x2*)(x8f + (((size_t)(bc * 32 + ms) * 4) << 10) +
                                    (size_t)lane * 16);  // += 512 /iter
  const f16* pG2 = xtf + ((((size_t)bc * 16) * 2 + ms) * 8) * 512 +
                   (size_t)lane * 8;  // += 8192 /iter
  const uint4* pBT = (const uint4*)betaTf + (size_t)(ms * 4096 + it * 128) +
                     lane;  // += 8192 /iter

  f32x16 o[4];
#pragma unroll
  for (int dt = 0; dt < 4; ++dt)
#pragma unroll
    for (int z = 0; z < 16; ++z) o[dt][z] = 0.f;

  // preload iter-0 GEMM1 A-frags
  i64 a8a[8], a8b[8];
#pragma unroll
  for (int g = 0; g < 4; ++g) {
    i64x2 v = pG1[g * 64];
    a8a[2 * g] = v[0];
    a8a[2 * g + 1] = v[1];
  }
  pG1 += 512;

  auto body = [&](i64* cur, i64* nxt, bool pf) {
    // beta (consumed after GEMM1) — issued first, fully coalesced
    uint4 bq0 = pBT[0];
    uint4 bq1 = pBT[64];
    pBT += 8192;
    // GEMM2 A-frags (consumed last)
    f16x8 g2[8];
#pragma unroll
    for (int pd = 0; pd < 8; ++pd) g2[pd] = *(const f16x8*)(pG2 + pd * 512);
    pG2 += 8192;
    // prefetch next iter's GEMM1 A-frags
    if (pf) {
#pragma unroll
      for (int g = 0; g < 4; ++g) {
        i64x2 v = pG1[g * 64];
        nxt[2 * g] = v[0];
        nxt[2 * g + 1] = v[1];
      }
      pG1 += 512;
    }

    // GEMM1 (fp8): S^T, K=128 (cur was loaded last iter -> no stall)
    f32x16 s;
#pragma unroll
    for (int z = 0; z < 16; ++z) s[z] = 0.f;
#pragma unroll
    for (int kk = 0; kk < 8; ++kk)
      s = __builtin_amdgcn_mfma_f32_32x32x16_fp8_fp8(cur[kk], xq8[kk], s, 0, 0,
                                                     0);

    // sigmoid -> packed f16 pairs
    uint bvp[8] = {bq0.x, bq0.y, bq0.z, bq0.w, bq1.x, bq1.y, bq1.z, bq1.w};
    float pk[8];
#pragma unroll
    for (int rp = 0; rp < 8; ++rp) {
      f16x2v bh = __builtin_bit_cast(f16x2v, bvp[rp]);
      float e0 = __builtin_amdgcn_exp2f((float)bh[0] * s[2 * rp]);
      float e1 = __builtin_amdgcn_exp2f((float)bh[1] * s[2 * rp + 1]);
      float p0 = __builtin_amdgcn_rcpf(1.0f + e0);
      float p1 = __builtin_amdgcn_rcpf(1.0f + e1);
      pk[rp] = __builtin_bit_cast(float, __builtin_amdgcn_cvt_pkrtz(p0, p1));
    }
    float qk[8];
#pragma unroll
    for (int rp = 0; rp < 8; ++rp) qk[rp] = __shfl_xor(pk[rp], 32);
    PFrag bt0, bt1;
    bt0.f[0] = hi ? qk[2] : pk[0];
    bt0.f[1] = hi ? qk[3] : pk[1];
    bt0.f[2] = hi ? pk[2] : qk[0];
    bt0.f[3] = hi ? pk[3] : qk[1];
    bt1.f[0] = hi ? qk[6] : pk[4];
    bt1.f[1] = hi ? qk[7] : pk[5];
    bt1.f[2] = hi ? pk[6] : qk[4];
    bt1.f[3] = hi ? pk[7] : qk[5];

    // GEMM2 (f16): O^T += X^T . P
#pragma unroll
    for (int dt = 0; dt < 4; ++dt) {
      o[dt] =
          __builtin_amdgcn_mfma_f32_32x32x16_f16(g2[dt], bt0.h, o[dt], 0, 0, 0);
      o[dt] = __builtin_amdgcn_mfma_f32_32x32x16_f16(g2[4 + dt], bt1.h, o[dt],
                                                     0, 0, 0);
    }
  };

#pragma unroll 1
  for (int mi = 0; mi < 16; mi += 2) {
    body(a8a, a8b, true);
    body(a8b, a8a, mi + 2 < 16);
  }

  // epilogue: pair-reduce (ms 0 + 1) + transpose via LDS, coalesced store
  __syncthreads();
  if (ms == 0) {
#pragma unroll
    for (int dt = 0; dt < 4; ++dt)
#pragma unroll
      for (int r = 0; r < 16; ++r) {
        int rowl = (r & 3) + 8 * (r >> 2) + 4 * hi;
        sO[(i_str + l31) * 132 + dt * 32 + rowl] = o[dt][r];
      }
  }
  __syncthreads();
  if (ms == 1) {
#pragma unroll
    for (int dt = 0; dt < 4; ++dt)
#pragma unroll
      for (int r = 0; r < 16; ++r) {
        int rowl = (r & 3) + 8 * (r >> 2) + 4 * hi;
        sO[(i_str + l31) * 132 + dt * 32 + rowl] += o[dt][r];
      }
  }
  __syncthreads();
  float* og = out + ((size_t)bc * NTOK + q0) * DDIM;
#pragma unroll
  for (int k = 0; k < 8; ++k) {
    int idx = t + 256 * k;
    int row = idx >> 5;
    int c4 = idx & 31;
    *(float4*)(og + (size_t)row * DDIM + c4 * 4) =
        *(const float4*)(sO + row * 132 + c4 * 4);
  }
}

extern "C" void kernel_launch(void* const* d_in, const int* in_sizes, int n_in,
                              void* d_out, int out_size, void* d_ws,
                              size_t ws_size, hipStream_t stream) {
  const float* x = (const float*)d_in[0];
  const float* beta = (const float*)d_in[1];
  float* out = (float*)d_out;

  char* ws = (char*)d_ws;
  unsigned char* x8f = (unsigned char*)ws;  // 8 MB  (fp8 fragment layout)
  f16* xtf = (f16*)(ws + (8 << 20));        // 16 MB (f16 X^T fragment layout)
  uint* betaTf = (uint*)(ws + (24 << 20));  // 2 MB  (beta fragment layout)

  prep_fused<<<1280, 256, 0, stream>>>(x, beta, x8f, xtf, betaTf);
  cos_att_main<<<1024, 256, 0, stream>>>(x8f, xtf, betaTf, out);
}